// Round 6
// baseline (241.328 us; speedup 1.0000x reference)
//
#include <hip/hip_runtime.h>
#include <hip/hip_bf16.h>
#include <math.h>

#define D_MODEL 1024
#define NHEADS  16
#define DK      64
#define SEQ     2048
#define BATCH   2
#define MROWS   4096   // BATCH*SEQ
#define NT2     (SEQ/32)   // 64 q-tiles of 32 rows

typedef unsigned short ushort_t;
using short8 = __attribute__((ext_vector_type(8))) short;
using f32x4  = __attribute__((ext_vector_type(4))) float;

__device__ __forceinline__ ushort_t f2bf(float x) {
    unsigned u = __float_as_uint(x);
    u = (u + 0x7FFFu + ((u >> 16) & 1u)) >> 16;   // RNE
    return (ushort_t)u;
}

// pack 2 floats -> 2 bf16 in one uint (v_cvt_pk_bf16_f32 on gfx950)
__device__ __forceinline__ unsigned pk2(float a, float b) {
    __hip_bfloat162 h = __float22bfloat162_rn(float2{a, b});
    unsigned u;
    __builtin_memcpy(&u, &h, 4);
    return u;
}

// async global->LDS, 16B per lane; LDS dest = wave-uniform base + lane*16
__device__ __forceinline__ void gll16(const ushort_t* g, ushort_t* l) {
    __builtin_amdgcn_global_load_lds(
        (const __attribute__((address_space(1))) void*)(g),
        (__attribute__((address_space(3))) void*)(l), 16, 0, 0);
}

// ---------------------------------------------------------------------------
// fp32 -> bf16 conversion, 7 tensors in one launch (blockIdx.y selects).
// ---------------------------------------------------------------------------
__global__ __launch_bounds__(256) void cvt_bf16(
    const float* s0, const float* s1, const float* s2, const float* s3,
    const float* s4, const float* s5, const float* s6,
    ushort_t* d0, ushort_t* d1, ushort_t* d2, ushort_t* d3,
    ushort_t* d4, ushort_t* d5, ushort_t* d6, int nIn, int nW)
{
    const float* s; ushort_t* d; int n;
    switch (blockIdx.y) {
        case 0: s = s0; d = d0; n = nIn; break;
        case 1: s = s1; d = d1; n = nIn; break;
        case 2: s = s2; d = d2; n = nIn; break;
        case 3: s = s3; d = d3; n = nW;  break;
        case 4: s = s4; d = d4; n = nW;  break;
        case 5: s = s5; d = d5; n = nW;  break;
        default: s = s6; d = d6; n = nW; break;
    }
    int i = (blockIdx.x * 256 + threadIdx.x) * 4;
    if (i < n) {
        float4 v = *(const float4*)&s[i];
        ushort4 o;
        o.x = f2bf(v.x); o.y = f2bf(v.y); o.z = f2bf(v.z); o.w = f2bf(v.w);
        *(ushort4*)&d[i] = o;
    }
}

// ---------------------------------------------------------------------------
// bf16 MFMA GEMM (QKV):  128x128 tile, BK=64, single-buffered gll16.
// MODE 0: C[M,N] = (A @ W^T + bias)*oscale, bf16 row-major out.
// MODE 1 (V^T): transposed gemm — A'=Wv (channels), B'=Vb (tokens) — the
//   standard epilogue emits rows of V^T[bh][d][s], coalesced stores.
// ---------------------------------------------------------------------------
struct GemmArgs { const ushort_t* A; const ushort_t* W; const float* bias;
                  void* C; int mode; float oscale; };

template<int MODE>
__device__ __forceinline__ void gemm_core(const GemmArgs& ga,
                                          ushort_t* As, ushort_t* Bs)
{
    const int tid  = threadIdx.x;
    const int w    = tid >> 6, lane = tid & 63;
    const int quad = lane >> 4, lx = lane & 15;
    const int mw = (w >> 1) * 64, nw = (w & 1) * 64;
    const int bm = (MODE == 1 ? blockIdx.y : blockIdx.x) * 128;
    const int bn = (MODE == 1 ? blockIdx.x : blockIdx.y) * 128;
    const int K = D_MODEL;

    f32x4 acc[4][4];
#pragma unroll
    for (int mt = 0; mt < 4; ++mt)
#pragma unroll
        for (int nt = 0; nt < 4; ++nt)
            acc[mt][nt] = (f32x4){0.f, 0.f, 0.f, 0.f};

    float4 b4[4];
    float  bfr[4];
#pragma unroll
    for (int i = 0; i < 4; ++i) {
        if (MODE == 0) b4[i]  = *(const float4*)&ga.bias[bn + nw + i * 16 + quad * 4];
        else           bfr[i] = ga.bias[bm + mw + i * 16 + lx];   // per-row bias
    }

    for (int k0 = 0; k0 < K; k0 += 64) {
        __syncthreads();
#pragma unroll
        for (int i = 0; i < 4; ++i) {
            int r0 = (w * 4 + i) * 8;
            int rl = r0 + (lane >> 3);
            int g  = (lane & 7) ^ (rl & 7);
            gll16(&ga.A[(size_t)(bm + rl) * K + k0 + g * 8], &As[r0 * 64]);
            gll16(&ga.W[(size_t)(bn + rl) * K + k0 + g * 8], &Bs[r0 * 64]);
        }
        __syncthreads();

#pragma unroll
        for (int ks = 0; ks < 2; ++ks) {
            short8 af[4], bf[4];
#pragma unroll
            for (int mt = 0; mt < 4; ++mt) {
                int r = mw + mt * 16 + lx;
                af[mt] = *(const short8*)&As[r * 64 + (((ks * 4 + quad) ^ (r & 7)) << 3)];
            }
#pragma unroll
            for (int nt = 0; nt < 4; ++nt) {
                int r = nw + nt * 16 + lx;
                bf[nt] = *(const short8*)&Bs[r * 64 + (((ks * 4 + quad) ^ (r & 7)) << 3)];
            }
#pragma unroll
            for (int mt = 0; mt < 4; ++mt)
#pragma unroll
                for (int nt = 0; nt < 4; ++nt)
                    acc[mt][nt] = __builtin_amdgcn_mfma_f32_16x16x32_bf16(
                        bf[nt], af[mt], acc[mt][nt], 0, 0, 0);
        }
    }

    if (MODE == 0) {
        ushort_t* C = (ushort_t*)ga.C;
        const float os = ga.oscale;
#pragma unroll
        for (int mt = 0; mt < 4; ++mt) {
            int m = bm + mw + mt * 16 + lx;
#pragma unroll
            for (int nt = 0; nt < 4; ++nt) {
                int n0 = bn + nw + nt * 16 + quad * 4;
                uint2 u;
                u.x = pk2((acc[mt][nt][0] + b4[nt].x) * os, (acc[mt][nt][1] + b4[nt].y) * os);
                u.y = pk2((acc[mt][nt][2] + b4[nt].z) * os, (acc[mt][nt][3] + b4[nt].w) * os);
                *(uint2*)&C[(size_t)m * D_MODEL + n0] = u;
            }
        }
    } else {
        ushort_t* C = (ushort_t*)ga.C;
#pragma unroll
        for (int mt = 0; mt < 4; ++mt) {
            int ch = bm + mw + mt * 16 + lx;
            int h = ch >> 6, d = ch & 63;
            float bb = bfr[mt];
#pragma unroll
            for (int nt = 0; nt < 4; ++nt) {
                int n0 = bn + nw + nt * 16 + quad * 4;
                int b = n0 >> 11, s0 = n0 & 2047;
                uint2 u;
                u.x = pk2(acc[mt][nt][0] + bb, acc[mt][nt][1] + bb);
                u.y = pk2(acc[mt][nt][2] + bb, acc[mt][nt][3] + bb);
                *(uint2*)&C[((size_t)(b * NHEADS + h) * DK + d) * SEQ + s0] = u;
            }
        }
    }
}

__global__ __launch_bounds__(256) void gemm_mfma(GemmArgs g0, GemmArgs g1, GemmArgs g2)
{
    __shared__ ushort_t As[128 * 64];
    __shared__ ushort_t Bs[128 * 64];
    GemmArgs ga = (blockIdx.z == 0) ? g0 : ((blockIdx.z == 1) ? g1 : g2);
    if (ga.mode == 0) gemm_core<0>(ga, As, Bs);
    else              gemm_core<1>(ga, As, Bs);
}

// ---------------------------------------------------------------------------
// O-projection GEMM: out[M,N] = Hc @ Wo^T + bo, fp32 out.
// ---------------------------------------------------------------------------
__global__ __launch_bounds__(256) void gemm_o(
    const ushort_t* __restrict__ A, const ushort_t* __restrict__ W,
    const float* __restrict__ bias, float* __restrict__ C)
{
    __shared__ ushort_t As[64 * 64];
    __shared__ ushort_t Bs[128 * 64];

    const int tid  = threadIdx.x;
    const int w    = tid >> 6, lane = tid & 63;
    const int quad = lane >> 4, lx = lane & 15;
    const int mw = (w >> 1) * 32, nw = (w & 1) * 64;
    const int bm = blockIdx.x * 64, bn = blockIdx.y * 128;
    const int K = D_MODEL;

    f32x4 acc[2][4];
#pragma unroll
    for (int mt = 0; mt < 2; ++mt)
#pragma unroll
        for (int nt = 0; nt < 4; ++nt)
            acc[mt][nt] = (f32x4){0.f, 0.f, 0.f, 0.f};

    float4 b4[4];
#pragma unroll
    for (int nt = 0; nt < 4; ++nt)
        b4[nt] = *(const float4*)&bias[bn + nw + nt * 16 + quad * 4];

    for (int k0 = 0; k0 < K; k0 += 64) {
        __syncthreads();
#pragma unroll
        for (int i = 0; i < 2; ++i) {
            int r0 = (i * 4 + w) * 8;
            int rl = r0 + (lane >> 3);
            int g  = (lane & 7) ^ (rl & 7);
            gll16(&A[(size_t)(bm + rl) * K + k0 + g * 8], &As[r0 * 64]);
        }
#pragma unroll
        for (int i = 0; i < 4; ++i) {
            int r0 = (i * 4 + w) * 8;
            int rl = r0 + (lane >> 3);
            int g  = (lane & 7) ^ (rl & 7);
            gll16(&W[(size_t)(bn + rl) * K + k0 + g * 8], &Bs[r0 * 64]);
        }
        __syncthreads();

#pragma unroll
        for (int ks = 0; ks < 2; ++ks) {
            short8 af[2], bf[4];
#pragma unroll
            for (int mt = 0; mt < 2; ++mt) {
                int r = mw + mt * 16 + lx;
                af[mt] = *(const short8*)&As[r * 64 + (((ks * 4 + quad) ^ (r & 7)) << 3)];
            }
#pragma unroll
            for (int nt = 0; nt < 4; ++nt) {
                int r = nw + nt * 16 + lx;
                bf[nt] = *(const short8*)&Bs[r * 64 + (((ks * 4 + quad) ^ (r & 7)) << 3)];
            }
#pragma unroll
            for (int mt = 0; mt < 2; ++mt)
#pragma unroll
                for (int nt = 0; nt < 4; ++nt)
                    acc[mt][nt] = __builtin_amdgcn_mfma_f32_16x16x32_bf16(
                        bf[nt], af[mt], acc[mt][nt], 0, 0, 0);
        }
    }

#pragma unroll
    for (int mt = 0; mt < 2; ++mt) {
        int m = bm + mw + mt * 16 + lx;
#pragma unroll
        for (int nt = 0; nt < 4; ++nt) {
            int n0 = bn + nw + nt * 16 + quad * 4;
            float4 v;
            v.x = acc[mt][nt][0] + b4[nt].x;
            v.y = acc[mt][nt][1] + b4[nt].y;
            v.z = acc[mt][nt][2] + b4[nt].z;
            v.w = acc[mt][nt][3] + b4[nt].w;
            *(float4*)&C[(size_t)m * D_MODEL + n0] = v;
        }
    }
}

// ---------------------------------------------------------------------------
// bf16 MFMA causal flash attention — r15: REGISTER-DIRECT K/V (no K/V LDS,
// no barriers, no manual waitcnt). Rationale (r5 counters + arithmetic):
// r13's DS-read demand (18 b128/wave-iter) ≈ 26µs of its 46µs; staging DMA
// +3.5µs; and the 23% occupancy == static qt-length spread (66/32 ≈ 2.06
// resident blocks, no backfill). K/V are L2-resident per XCD (2MB, proven
// by FETCH collapse in r1), and fragment gathers read full 64B lines
// (4 quads x 16B consecutive per lx). So: load K/V fragments straight
// global->VGPR. One wave per block, 32 q-rows (2 groups of 16) so each
// K/V fragment feeds 2x the math. kf double-set prefetched one iteration
// ahead (~900cyc >> 200cyc L2 latency); vf single-set issued right after
// QK (~400cyc before PV use). 2048 blocks > 1024 slots -> dynamic
// backfill; LPT order (long tiles first); XCD head-grouping kept.
// LDS = 2KB (P scratch only).
// ---------------------------------------------------------------------------
#define FLASH_BODY(CUR, NXT)                                                  \
{                                                                             \
    /* S^T = K Q^T for both groups; CUR holds K(kt) fragments */              \
    f32x4 s0[4], s1[4];                                                       \
    __builtin_amdgcn_s_setprio(1);                                            \
    _Pragma("unroll")                                                         \
    for (int nt = 0; nt < 4; ++nt) {                                          \
        f32x4 z = (f32x4){0.f, 0.f, 0.f, 0.f};                                \
        z = __builtin_amdgcn_mfma_f32_16x16x32_bf16(CUR[nt][0], qf[0][0], z, 0, 0, 0); \
        z = __builtin_amdgcn_mfma_f32_16x16x32_bf16(CUR[nt][1], qf[0][1], z, 0, 0, 0); \
        s0[nt] = z;                                                           \
        f32x4 y = (f32x4){0.f, 0.f, 0.f, 0.f};                                \
        y = __builtin_amdgcn_mfma_f32_16x16x32_bf16(CUR[nt][0], qf[1][0], y, 0, 0, 0); \
        y = __builtin_amdgcn_mfma_f32_16x16x32_bf16(CUR[nt][1], qf[1][1], y, 0, 0, 0); \
        s1[nt] = y;                                                           \
    }                                                                         \
    __builtin_amdgcn_s_setprio(0);                                            \
    /* issue V(kt) (used ~softmax-time later), then prefetch K(kt+1) */       \
    _Pragma("unroll")                                                         \
    for (int nt = 0; nt < 4; ++nt) {                                          \
        size_t vr = vbase + (size_t)(nt * 16 + lx) * SEQ + kt * 64 + quad * 8;\
        vf[nt][0] = *(const short8*)&Vt[vr];                                  \
        vf[nt][1] = *(const short8*)&Vt[vr + 32];                             \
    }                                                                         \
    if (kt < ktl) {                                                           \
        _Pragma("unroll")                                                     \
        for (int nt = 0; nt < 4; ++nt) {                                      \
            size_t kr = qbase + (size_t)((kt + 1) * 64 + nt * 16 + lx) * D_MODEL + quad * 8; \
            NXT[nt][0] = *(const short8*)&Kp[kr];                             \
            NXT[nt][1] = *(const short8*)&Kp[kr + 32];                        \
        }                                                                     \
    }                                                                         \
    /* causal mask on the last k-tile */                                      \
    if (kt == ktl) {                                                          \
        int qr0 = t2 * 32 + lx - ktl * 64;                                    \
        _Pragma("unroll")                                                     \
        for (int nt = 0; nt < 4; ++nt)                                        \
            _Pragma("unroll")                                                 \
            for (int r = 0; r < 4; ++r) {                                     \
                int kk = nt * 16 + quad * 4 + r;                              \
                if (kk > qr0)      s0[nt][r] = -INFINITY;                     \
                if (kk > qr0 + 16) s1[nt][r] = -INFINITY;                     \
            }                                                                 \
    }                                                                         \
    /* online softmax, group 0 (defer-max gate; per-lane partial l) */        \
    {                                                                         \
        float a0 = fmaxf(fmaxf(s0[0][0], s0[0][1]), fmaxf(s0[0][2], s0[0][3])); \
        float a1 = fmaxf(fmaxf(s0[1][0], s0[1][1]), fmaxf(s0[1][2], s0[1][3])); \
        float a2 = fmaxf(fmaxf(s0[2][0], s0[2][1]), fmaxf(s0[2][2], s0[2][3])); \
        float a3 = fmaxf(fmaxf(s0[3][0], s0[3][1]), fmaxf(s0[3][2], s0[3][3])); \
        float lm = fmaxf(fmaxf(a0, a1), fmaxf(a2, a3));                       \
        if (__any(lm > mg[0] + 8.f)) {                                        \
            float tm = fmaxf(lm, __shfl_xor(lm, 16, 64));                     \
            tm = fmaxf(tm, __shfl_xor(tm, 32, 64));                          \
            float mnew = fmaxf(mg[0], tm);                                    \
            float alpha = __builtin_amdgcn_exp2f(mg[0] - mnew);               \
            mg[0] = mnew; lg[0] *= alpha;                                     \
            _Pragma("unroll")                                                 \
            for (int nt = 0; nt < 4; ++nt)                                    \
                _Pragma("unroll")                                             \
                for (int r = 0; r < 4; ++r) O[0][nt][r] *= alpha;             \
        }                                                                     \
        _Pragma("unroll")                                                     \
        for (int nt = 0; nt < 4; ++nt)                                        \
            _Pragma("unroll")                                                 \
            for (int r = 0; r < 4; ++r)                                       \
                s0[nt][r] = __builtin_amdgcn_exp2f(s0[nt][r] - mg[0]);        \
        lg[0] += ((s0[0][0]+s0[0][1])+(s0[0][2]+s0[0][3]))                    \
               + ((s0[1][0]+s0[1][1])+(s0[1][2]+s0[1][3]))                    \
               + ((s0[2][0]+s0[2][1])+(s0[2][2]+s0[2][3]))                    \
               + ((s0[3][0]+s0[3][1])+(s0[3][2]+s0[3][3]));                   \
    }                                                                         \
    /* online softmax, group 1 */                                             \
    {                                                                         \
        float a0 = fmaxf(fmaxf(s1[0][0], s1[0][1]), fmaxf(s1[0][2], s1[0][3])); \
        float a1 = fmaxf(fmaxf(s1[1][0], s1[1][1]), fmaxf(s1[1][2], s1[1][3])); \
        float a2 = fmaxf(fmaxf(s1[2][0], s1[2][1]), fmaxf(s1[2][2], s1[2][3])); \
        float a3 = fmaxf(fmaxf(s1[3][0], s1[3][1]), fmaxf(s1[3][2], s1[3][3])); \
        float lm = fmaxf(fmaxf(a0, a1), fmaxf(a2, a3));                       \
        if (__any(lm > mg[1] + 8.f)) {                                        \
            float tm = fmaxf(lm, __shfl_xor(lm, 16, 64));                     \
            tm = fmaxf(tm, __shfl_xor(tm, 32, 64));                          \
            float mnew = fmaxf(mg[1], tm);                                    \
            float alpha = __builtin_amdgcn_exp2f(mg[1] - mnew);               \
            mg[1] = mnew; lg[1] *= alpha;                                     \
            _Pragma("unroll")                                                 \
            for (int nt = 0; nt < 4; ++nt)                                    \
                _Pragma("unroll")                                             \
                for (int r = 0; r < 4; ++r) O[1][nt][r] *= alpha;             \
        }                                                                     \
        _Pragma("unroll")                                                     \
        for (int nt = 0; nt < 4; ++nt)                                        \
            _Pragma("unroll")                                                 \
            for (int r = 0; r < 4; ++r)                                       \
                s1[nt][r] = __builtin_amdgcn_exp2f(s1[nt][r] - mg[1]);        \
        lg[1] += ((s1[0][0]+s1[0][1])+(s1[0][2]+s1[0][3]))                    \
               + ((s1[1][0]+s1[1][1])+(s1[1][2]+s1[1][3]))                    \
               + ((s1[2][0]+s1[2][1])+(s1[2][2]+s1[2][3]))                    \
               + ((s1[3][0]+s1[3][1])+(s1[3][2]+s1[3][3]));                   \
    }                                                                         \
    /* group 0: P round-trip + PV (vf shared by both groups) */               \
    {                                                                         \
        _Pragma("unroll")                                                     \
        for (int nt = 0; nt < 4; ++nt) {                                      \
            uint2 u;                                                          \
            u.x = pk2(s0[nt][0], s0[nt][1]);                                  \
            u.y = pk2(s0[nt][2], s0[nt][3]);                                  \
            *(uint2*)(Pb + ((nt * 32 + quad * 8) ^ hsw)) = u;                 \
        }                                                                     \
        short8 pf0 = *(const short8*)(Pb + ((quad * 16) ^ hsw));              \
        short8 pf1 = *(const short8*)(Pb + ((64 + quad * 16) ^ hsw));         \
        __builtin_amdgcn_s_setprio(1);                                        \
        _Pragma("unroll")                                                     \
        for (int nt = 0; nt < 4; ++nt) {                                      \
            O[0][nt] = __builtin_amdgcn_mfma_f32_16x16x32_bf16(vf[nt][0], pf0, O[0][nt], 0, 0, 0); \
            O[0][nt] = __builtin_amdgcn_mfma_f32_16x16x32_bf16(vf[nt][1], pf1, O[0][nt], 0, 0, 0); \
        }                                                                     \
        __builtin_amdgcn_s_setprio(0);                                        \
    }                                                                         \
    /* group 1: P round-trip + PV (same Ps region; same-wave DS in-order) */  \
    {                                                                         \
        _Pragma("unroll")                                                     \
        for (int nt = 0; nt < 4; ++nt) {                                      \
            uint2 u;                                                          \
            u.x = pk2(s1[nt][0], s1[nt][1]);                                  \
            u.y = pk2(s1[nt][2], s1[nt][3]);                                  \
            *(uint2*)(Pb + ((nt * 32 + quad * 8) ^ hsw)) = u;                 \
        }                                                                     \
        short8 pf0 = *(const short8*)(Pb + ((quad * 16) ^ hsw));              \
        short8 pf1 = *(const short8*)(Pb + ((64 + quad * 16) ^ hsw));         \
        __builtin_amdgcn_s_setprio(1);                                        \
        _Pragma("unroll")                                                     \
        for (int nt = 0; nt < 4; ++nt) {                                      \
            O[1][nt] = __builtin_amdgcn_mfma_f32_16x16x32_bf16(vf[nt][0], pf0, O[1][nt], 0, 0, 0); \
            O[1][nt] = __builtin_amdgcn_mfma_f32_16x16x32_bf16(vf[nt][1], pf1, O[1][nt], 0, 0, 0); \
        }                                                                     \
        __builtin_amdgcn_s_setprio(0);                                        \
    }                                                                         \
}

__global__ __launch_bounds__(64, 2) void flash_mfma(
    const ushort_t* __restrict__ Qp, const ushort_t* __restrict__ Kp,
    const ushort_t* __restrict__ Vt, ushort_t* __restrict__ Hc)
{
    __shared__ __align__(16) ushort_t Ps[16 * 64];   // 2KB P scratch (only LDS)

    // 2048 blocks: XCD c gets heads {c, c+8, c+16, c+24} (K/V 2MB, L2-fit);
    // t2 descending (LPT: 32-iter tiles dispatch first, short ones backfill).
    const int flat = blockIdx.x;              // 0..2047
    const int c  = flat & 7;                  // XCD
    const int b2 = (flat >> 3) & 3;
    const int sidx = flat >> 5;               // 0..63
    const int bh = c + (b2 << 3);
    const int t2 = NT2 - 1 - sidx;            // 63..0
    const int b = bh >> 4, h = bh & 15;

    const size_t qbase = (size_t)(b * SEQ) * D_MODEL + h * DK;
    const size_t vbase = (size_t)bh * DK * SEQ;

    const int lane = threadIdx.x;
    const int quad = lane >> 4, lx = lane & 15;
    const int ktl = (t2 * 32 + 31) >> 6;      // last 64-wide k-tile index

    // Q fragments for groups g=0,1 (rows t2*32 + g*16 + lx)
    short8 qf[2][2];
#pragma unroll
    for (int g = 0; g < 2; ++g) {
        size_t ro = qbase + (size_t)(t2 * 32 + g * 16 + lx) * D_MODEL + quad * 8;
        qf[g][0] = *(const short8*)&Qp[ro];
        qf[g][1] = *(const short8*)&Qp[ro + 32];
    }

    // per-lane P row base: pad-free 128B rows, XOR-16B swizzle on (lx&7)
    char* Pb = (char*)&Ps[0] + (lx << 7);
    const int hsw = (lx & 7) << 4;

    f32x4 O[2][4];
#pragma unroll
    for (int g = 0; g < 2; ++g)
#pragma unroll
        for (int nt = 0; nt < 4; ++nt)
            O[g][nt] = (f32x4){0.f, 0.f, 0.f, 0.f};
    float mg[2] = {-INFINITY, -INFINITY};
    float lg[2] = {0.f, 0.f};

    // K fragment double-set; V single-set (issued in-iter, used after softmax)
    short8 kfA[4][2], kfB[4][2], vf[4][2];
#pragma unroll
    for (int nt = 0; nt < 4; ++nt) {
        size_t kr = qbase + (size_t)(nt * 16 + lx) * D_MODEL + quad * 8;
        kfA[nt][0] = *(const short8*)&Kp[kr];
        kfA[nt][1] = *(const short8*)&Kp[kr + 32];
    }

    int kt = 0;
    for (;;) {
        FLASH_BODY(kfA, kfB);
        if (kt == ktl) break;
        ++kt;
        FLASH_BODY(kfB, kfA);
        if (kt == ktl) break;
        ++kt;
    }

    // epilogue: finish deferred l-reduce, write O rows (q = t2*32+g*16+lx)
#pragma unroll
    for (int g = 0; g < 2; ++g) {
        float l = lg[g];
        l += __shfl_xor(l, 16, 64);
        l += __shfl_xor(l, 32, 64);
        float invl = 1.f / l;
        size_t ro = qbase + (size_t)(t2 * 32 + g * 16 + lx) * D_MODEL;
#pragma unroll
        for (int nt = 0; nt < 4; ++nt) {
            uint2 u;
            u.x = pk2(O[g][nt][0] * invl, O[g][nt][1] * invl);
            u.y = pk2(O[g][nt][2] * invl, O[g][nt][3] * invl);
            *(uint2*)&Hc[ro + nt * 16 + quad * 4] = u;
        }
    }
}

extern "C" void kernel_launch(void* const* d_in, const int* in_sizes, int n_in,
                              void* d_out, int out_size, void* d_ws, size_t ws_size,
                              hipStream_t stream) {
    const float* inQ = (const float*)d_in[0];
    const float* inK = (const float*)d_in[1];
    const float* inV = (const float*)d_in[2];
    const float* Wq  = (const float*)d_in[3];
    const float* bq  = (const float*)d_in[4];
    const float* Wk  = (const float*)d_in[5];
    const float* bk  = (const float*)d_in[6];
    const float* Wv  = (const float*)d_in[7];
    const float* bv  = (const float*)d_in[8];
    const float* Wo  = (const float*)d_in[9];
    const float* bo  = (const float*)d_in[10];
    float* out = (float*)d_out;

    const size_t NI = (size_t)MROWS * D_MODEL;      // 4M
    const size_t NW = (size_t)D_MODEL * D_MODEL;    // 1M
    ushort_t* ws  = (ushort_t*)d_ws;
    ushort_t* Qb  = ws;                // bf16 inputs
    ushort_t* Kb  = Qb  + NI;
    ushort_t* Vb  = Kb  + NI;
    ushort_t* Wqb = Vb  + NI;          // bf16 weights
    ushort_t* Wkb = Wqb + NW;
    ushort_t* Wvb = Wkb + NW;
    ushort_t* Wob = Wvb + NW;
    ushort_t* Qp  = Wob + NW;          // projections
    ushort_t* Kp  = Qp  + NI;
    ushort_t* Vtg = Kp  + NI;          // V^T [B*H][DK][SEQ]
    ushort_t* Hc  = Vtg + NI;

    // fp32 -> bf16 (all 7 tensors, one launch)
    cvt_bf16<<<dim3(NI / 1024, 7), 256, 0, stream>>>(
        inQ, inK, inV, Wq, Wk, Wv, Wo,
        Qb, Kb, Vb, Wqb, Wkb, Wvb, Wob, (int)NI, (int)NW);

    // fused QKV projection; Q pre-scaled by 1/sqrt(dk)*log2(e).
    // V^T via transposed gemm: A'=Wvb (rows=channels), W'=Vb (rows=tokens).
    const float qsc = 0.125f * 1.44269504088896340736f;
    GemmArgs aq{Qb, Wqb, bq, (void*)Qp, 0, qsc};
    GemmArgs ak{Kb, Wkb, bk, (void*)Kp, 0, 1.0f};
    GemmArgs av{Wvb, Vb, bv, (void*)Vtg, 1, 1.0f};
    gemm_mfma<<<dim3(MROWS / 128, D_MODEL / 128, 3), 256, 0, stream>>>(aq, ak, av);

    // attention: register-direct K/V, 2048 one-wave blocks, no barriers
    flash_mfma<<<dim3(NT2 * BATCH * NHEADS), 64, 0, stream>>>(Qp, Kp, Vtg, Hc);

    // output projection (fp32 out), 64x128 single-buffer tiles, 512 blocks
    gemm_o<<<dim3(MROWS / 64, D_MODEL / 128), 256, 0, stream>>>(Hc, Wob, bo, out);
}

// Round 7
// 223.639 us; speedup vs baseline: 1.0791x; 1.0791x over previous
//
#include <hip/hip_runtime.h>
#include <hip/hip_bf16.h>
#include <math.h>

#define D_MODEL 1024
#define NHEADS  16
#define DK      64
#define SEQ     2048
#define BATCH   2
#define MROWS   4096   // BATCH*SEQ
#define NQT     (SEQ/64)   // 32 q-tiles

typedef unsigned short ushort_t;
using short8 = __attribute__((ext_vector_type(8))) short;
using f32x4  = __attribute__((ext_vector_type(4))) float;

__device__ __forceinline__ ushort_t f2bf(float x) {
    unsigned u = __float_as_uint(x);
    u = (u + 0x7FFFu + ((u >> 16) & 1u)) >> 16;   // RNE
    return (ushort_t)u;
}

// pack 2 floats -> 2 bf16 in one uint (v_cvt_pk_bf16_f32 on gfx950)
__device__ __forceinline__ unsigned pk2(float a, float b) {
    __hip_bfloat162 h = __float22bfloat162_rn(float2{a, b});
    unsigned u;
    __builtin_memcpy(&u, &h, 4);
    return u;
}

// async global->LDS, 16B per lane; LDS dest = wave-uniform base + lane*16
__device__ __forceinline__ void gll16(const ushort_t* g, ushort_t* l) {
    __builtin_amdgcn_global_load_lds(
        (const __attribute__((address_space(1))) void*)(g),
        (__attribute__((address_space(3))) void*)(l), 16, 0, 0);
}

// ---------------------------------------------------------------------------
// fp32 -> bf16 conversion — WEIGHTS ONLY (r16: input conversion fused into
// the QKV GEMM staging; this pass feeds Wq/Wk/Wv bf16 to gemm_mfma's weight
// side and Wo bf16 to gemm_o).
// ---------------------------------------------------------------------------
__global__ __launch_bounds__(256) void cvt_bf16(
    const float* s0, const float* s1, const float* s2, const float* s3,
    ushort_t* d0, ushort_t* d1, ushort_t* d2, ushort_t* d3)
{
    const float* s; ushort_t* d;
    switch (blockIdx.y) {
        case 0: s = s0; d = d0; break;
        case 1: s = s1; d = d1; break;
        case 2: s = s2; d = d2; break;
        default: s = s3; d = d3; break;
    }
    int i = (blockIdx.x * 256 + threadIdx.x) * 4;
    float4 v = *(const float4*)&s[i];
    ushort4 o;
    o.x = f2bf(v.x); o.y = f2bf(v.y); o.z = f2bf(v.z); o.w = f2bf(v.w);
    *(ushort4*)&d[i] = o;
}

// ---------------------------------------------------------------------------
// bf16 MFMA GEMM (QKV) with FUSED fp32->bf16 input staging (r16).
// 128x128 tile, BK=64. Weight side: bf16 via async gll16 (issued first so
// the DMA overlaps the fp32 load latency). Input side: fp32 loaded to regs,
// cvt_pk to bf16, ds_write_b128 with the row-XOR col mapping
// LDS[r][c] = G[r][c ^ (r&7)] — identical layout to the gll16 path, so the
// MFMA read path is unchanged. Write col-block = (lane&7)^(row&7) varies
// per row -> bank-conflict-free b128 writes.
// MODE 0: C = (X @ W^T + bias)*oscale, bf16 row-major (X = inQ/inK fp32).
// MODE 1 (V^T): transposed gemm — A'=Wv (channels, gll16), B'=inV fp32
//   (tokens, fused-cvt staging); epilogue emits V^T[bh][d][s] coalesced.
// ---------------------------------------------------------------------------
struct GemmArgs { const float* X; const ushort_t* Wb; const float* bias;
                  void* C; int mode; float oscale; };

template<int MODE>
__device__ __forceinline__ void gemm_core(const GemmArgs& ga,
                                          ushort_t* As, ushort_t* Bs)
{
    const int tid  = threadIdx.x;
    const int w    = tid >> 6, lane = tid & 63;
    const int quad = lane >> 4, lx = lane & 15;
    const int mw = (w >> 1) * 64, nw = (w & 1) * 64;
    const int bm = (MODE == 1 ? blockIdx.y : blockIdx.x) * 128;
    const int bn = (MODE == 1 ? blockIdx.x : blockIdx.y) * 128;
    const int K = D_MODEL;

    // fp32 input side goes to As (MODE0) or Bs (MODE1); weights to the other
    ushort_t* Xs = (MODE == 0) ? As : Bs;
    ushort_t* Ws = (MODE == 0) ? Bs : As;
    const int xrow0 = (MODE == 0) ? bm : bn;   // row base of the fp32 tile
    const int wrow0 = (MODE == 0) ? bn : bm;   // row base of the weight tile

    f32x4 acc[4][4];
#pragma unroll
    for (int mt = 0; mt < 4; ++mt)
#pragma unroll
        for (int nt = 0; nt < 4; ++nt)
            acc[mt][nt] = (f32x4){0.f, 0.f, 0.f, 0.f};

    float4 b4[4];
    float  bfr[4];
#pragma unroll
    for (int i = 0; i < 4; ++i) {
        if (MODE == 0) b4[i]  = *(const float4*)&ga.bias[bn + nw + i * 16 + quad * 4];
        else           bfr[i] = ga.bias[bm + mw + i * 16 + lx];   // per-row bias
    }

    for (int k0 = 0; k0 < K; k0 += 64) {
        __syncthreads();
        // weight side first: async DMA runs during the fp32 loads below
#pragma unroll
        for (int i = 0; i < 4; ++i) {
            int r0 = (w * 4 + i) * 8;
            int rl = r0 + (lane >> 3);
            int g  = (lane & 7) ^ (rl & 7);
            gll16(&ga.Wb[(size_t)(wrow0 + rl) * K + k0 + g * 8], &Ws[r0 * 64]);
        }
        // fused-cvt input side: fp32 -> regs -> bf16 -> ds_write_b128
#pragma unroll
        for (int i = 0; i < 4; ++i) {
            int r0 = (w * 4 + i) * 8;
            int rl = r0 + (lane >> 3);
            int cb = lane & 7;
            const float4* p = (const float4*)&ga.X[(size_t)(xrow0 + rl) * K + k0 + cb * 8];
            float4 v0 = p[0], v1 = p[1];
            uint4 uu;
            uu.x = pk2(v0.x, v0.y); uu.y = pk2(v0.z, v0.w);
            uu.z = pk2(v1.x, v1.y); uu.w = pk2(v1.z, v1.w);
            *(uint4*)&Xs[rl * 64 + ((cb ^ (rl & 7)) * 8)] = uu;
        }
        __syncthreads();

#pragma unroll
        for (int ks = 0; ks < 2; ++ks) {
            short8 af[4], bf[4];
#pragma unroll
            for (int mt = 0; mt < 4; ++mt) {
                int r = mw + mt * 16 + lx;
                af[mt] = *(const short8*)&As[r * 64 + (((ks * 4 + quad) ^ (r & 7)) << 3)];
            }
#pragma unroll
            for (int nt = 0; nt < 4; ++nt) {
                int r = nw + nt * 16 + lx;
                bf[nt] = *(const short8*)&Bs[r * 64 + (((ks * 4 + quad) ^ (r & 7)) << 3)];
            }
#pragma unroll
            for (int mt = 0; mt < 4; ++mt)
#pragma unroll
                for (int nt = 0; nt < 4; ++nt)
                    acc[mt][nt] = __builtin_amdgcn_mfma_f32_16x16x32_bf16(
                        bf[nt], af[mt], acc[mt][nt], 0, 0, 0);
        }
    }

    if (MODE == 0) {
        ushort_t* C = (ushort_t*)ga.C;
        const float os = ga.oscale;
#pragma unroll
        for (int mt = 0; mt < 4; ++mt) {
            int m = bm + mw + mt * 16 + lx;
#pragma unroll
            for (int nt = 0; nt < 4; ++nt) {
                int n0 = bn + nw + nt * 16 + quad * 4;
                uint2 u;
                u.x = pk2((acc[mt][nt][0] + b4[nt].x) * os, (acc[mt][nt][1] + b4[nt].y) * os);
                u.y = pk2((acc[mt][nt][2] + b4[nt].z) * os, (acc[mt][nt][3] + b4[nt].w) * os);
                *(uint2*)&C[(size_t)m * D_MODEL + n0] = u;
            }
        }
    } else {
        // row = channel ch (h = ch>>6, d = ch&63); col = token n0 (b, s)
        ushort_t* C = (ushort_t*)ga.C;
#pragma unroll
        for (int mt = 0; mt < 4; ++mt) {
            int ch = bm + mw + mt * 16 + lx;
            int h = ch >> 6, d = ch & 63;
            float bb = bfr[mt];
#pragma unroll
            for (int nt = 0; nt < 4; ++nt) {
                int n0 = bn + nw + nt * 16 + quad * 4;
                int b = n0 >> 11, s0 = n0 & 2047;
                uint2 u;
                u.x = pk2(acc[mt][nt][0] + bb, acc[mt][nt][1] + bb);
                u.y = pk2(acc[mt][nt][2] + bb, acc[mt][nt][3] + bb);
                *(uint2*)&C[((size_t)(b * NHEADS + h) * DK + d) * SEQ + s0] = u;
            }
        }
    }
}

__global__ __launch_bounds__(256) void gemm_mfma(GemmArgs g0, GemmArgs g1, GemmArgs g2)
{
    __shared__ ushort_t As[128 * 64];
    __shared__ ushort_t Bs[128 * 64];
    GemmArgs ga = (blockIdx.z == 0) ? g0 : ((blockIdx.z == 1) ? g1 : g2);
    if (ga.mode == 0) gemm_core<0>(ga, As, Bs);
    else              gemm_core<1>(ga, As, Bs);
}

// ---------------------------------------------------------------------------
// O-projection GEMM: out[M,N] = Hc @ Wo^T + bo, fp32 out.
// ---------------------------------------------------------------------------
__global__ __launch_bounds__(256) void gemm_o(
    const ushort_t* __restrict__ A, const ushort_t* __restrict__ W,
    const float* __restrict__ bias, float* __restrict__ C)
{
    __shared__ ushort_t As[64 * 64];
    __shared__ ushort_t Bs[128 * 64];

    const int tid  = threadIdx.x;
    const int w    = tid >> 6, lane = tid & 63;
    const int quad = lane >> 4, lx = lane & 15;
    const int mw = (w >> 1) * 32, nw = (w & 1) * 64;
    const int bm = blockIdx.x * 64, bn = blockIdx.y * 128;
    const int K = D_MODEL;

    f32x4 acc[2][4];
#pragma unroll
    for (int mt = 0; mt < 2; ++mt)
#pragma unroll
        for (int nt = 0; nt < 4; ++nt)
            acc[mt][nt] = (f32x4){0.f, 0.f, 0.f, 0.f};

    float4 b4[4];
#pragma unroll
    for (int nt = 0; nt < 4; ++nt)
        b4[nt] = *(const float4*)&bias[bn + nw + nt * 16 + quad * 4];

    for (int k0 = 0; k0 < K; k0 += 64) {
        __syncthreads();
#pragma unroll
        for (int i = 0; i < 2; ++i) {
            int r0 = (i * 4 + w) * 8;
            int rl = r0 + (lane >> 3);
            int g  = (lane & 7) ^ (rl & 7);
            gll16(&A[(size_t)(bm + rl) * K + k0 + g * 8], &As[r0 * 64]);
        }
#pragma unroll
        for (int i = 0; i < 4; ++i) {
            int r0 = (i * 4 + w) * 8;
            int rl = r0 + (lane >> 3);
            int g  = (lane & 7) ^ (rl & 7);
            gll16(&W[(size_t)(bn + rl) * K + k0 + g * 8], &Bs[r0 * 64]);
        }
        __syncthreads();

#pragma unroll
        for (int ks = 0; ks < 2; ++ks) {
            short8 af[2], bf[4];
#pragma unroll
            for (int mt = 0; mt < 2; ++mt) {
                int r = mw + mt * 16 + lx;
                af[mt] = *(const short8*)&As[r * 64 + (((ks * 4 + quad) ^ (r & 7)) << 3)];
            }
#pragma unroll
            for (int nt = 0; nt < 4; ++nt) {
                int r = nw + nt * 16 + lx;
                bf[nt] = *(const short8*)&Bs[r * 64 + (((ks * 4 + quad) ^ (r & 7)) << 3)];
            }
#pragma unroll
            for (int mt = 0; mt < 2; ++mt)
#pragma unroll
                for (int nt = 0; nt < 4; ++nt)
                    acc[mt][nt] = __builtin_amdgcn_mfma_f32_16x16x32_bf16(
                        bf[nt], af[mt], acc[mt][nt], 0, 0, 0);
        }
    }

#pragma unroll
    for (int mt = 0; mt < 2; ++mt) {
        int m = bm + mw + mt * 16 + lx;
#pragma unroll
        for (int nt = 0; nt < 4; ++nt) {
            int n0 = bn + nw + nt * 16 + quad * 4;
            float4 v;
            v.x = acc[mt][nt][0] + b4[nt].x;
            v.y = acc[mt][nt][1] + b4[nt].y;
            v.z = acc[mt][nt][2] + b4[nt].z;
            v.w = acc[mt][nt][3] + b4[nt].w;
            *(float4*)&C[(size_t)m * D_MODEL + n0] = v;
        }
    }
}

// ---------------------------------------------------------------------------
// bf16 MFMA causal flash attention — EXACT r13 revert (best measured:
// 46.2µs, prediction-matched). 4-wave blocks, dbuf K/V via gll16, barriers;
// defer-max gate on per-lane max; per-lane partial l reduced in epilogue.
// Structure frozen: r12/r15 (1-wave, barrier-free variants) both regressed
// 2x — the 4-wave barrier structure's TLP is what hides K/V latency.
// ---------------------------------------------------------------------------
__device__ __forceinline__ void flash_tile(
    int qt, const size_t qbase, const size_t vbase,
    const ushort_t* __restrict__ Qp, const ushort_t* __restrict__ Kp,
    const ushort_t* __restrict__ Vt, ushort_t* __restrict__ Hc,
    ushort_t* Ks0, ushort_t* Ks1, ushort_t* Vs0, ushort_t* Vs1,
    ushort_t (*Ps)[16 * 64])
{
    const int tid  = threadIdx.x;
    const int w    = tid >> 6, lane = tid & 63;
    const int quad = lane >> 4, lx = lane & 15;

    // prologue: stage k-tile 0 into buffer 0
    {
#pragma unroll
        for (int i = 0; i < 2; ++i) {
            int r0 = (w + i * 4) * 8;
            int rl = r0 + (lane >> 3);
            int g  = (lane & 7) ^ (rl & 7);
            gll16(&Kp[qbase + (size_t)rl * D_MODEL + g * 8], &Ks0[r0 * 64]);
            gll16(&Vt[vbase + (size_t)rl * SEQ + g * 8], &Vs0[r0 * 64]);
        }
    }

    // Q fragments (row qt*64 + w*16 + lx), resident across all k-tiles
    short8 qf[2];
    {
        size_t ro = qbase + (size_t)(qt * 64 + w * 16 + lx) * D_MODEL + quad * 8;
        qf[0] = *(const short8*)&Qp[ro];
        qf[1] = *(const short8*)&Qp[ro + 32];
    }

    // per-wave P row base: pad-free 128B rows, XOR-16B swizzle on (lx&7)
    char* Pb = (char*)&Ps[w][0] + (lx << 7);
    const int hsw = (lx & 7) << 4;

    f32x4 O[4];           // O^T frags: d = nt*16+quad*4+r, q = lx
#pragma unroll
    for (int nt = 0; nt < 4; ++nt) O[nt] = (f32x4){0.f, 0.f, 0.f, 0.f};
    float mrow = -INFINITY, lrow = 0.f;   // mrow row-uniform; lrow PER-LANE partial
    const int qin = w * 16 + lx;          // q index within the 64-row tile

    for (int kt = 0; kt <= qt; ++kt) {
        ushort_t* Ks = (kt & 1) ? Ks1 : Ks0;
        ushort_t* Vs = (kt & 1) ? Vs1 : Vs0;

        // tile-kt loads were issued one full iteration ago
        asm volatile("s_waitcnt vmcnt(0)" ::: "memory");
        asm volatile("s_barrier" ::: "memory");

        // prefetch k-tile kt+1 into the other buffer (overlaps compute below)
        if (kt < qt) {
            ushort_t* Kn = (kt & 1) ? Ks0 : Ks1;
            ushort_t* Vn = (kt & 1) ? Vs0 : Vs1;
#pragma unroll
            for (int i = 0; i < 2; ++i) {
                int r0 = (w + i * 4) * 8;
                int rl = r0 + (lane >> 3);
                int g  = (lane & 7) ^ (rl & 7);
                gll16(&Kp[qbase + (size_t)((kt + 1) * 64 + rl) * D_MODEL + g * 8], &Kn[r0 * 64]);
                gll16(&Vt[vbase + (size_t)rl * SEQ + (kt + 1) * 64 + g * 8], &Vn[r0 * 64]);
            }
        }

        // S^T = K Q^T : s[nt][r] = S[q=lx][k = nt*16+quad*4+r]
        f32x4 s[4];
        __builtin_amdgcn_s_setprio(1);
#pragma unroll
        for (int nt = 0; nt < 4; ++nt) {
            int r = nt * 16 + lx;
            short8 kf0 = *(const short8*)&Ks[r * 64 + ((quad ^ (r & 7)) << 3)];
            short8 kf1 = *(const short8*)&Ks[r * 64 + (((4 + quad) ^ (r & 7)) << 3)];
            f32x4 z = (f32x4){0.f, 0.f, 0.f, 0.f};
            z = __builtin_amdgcn_mfma_f32_16x16x32_bf16(kf0, qf[0], z, 0, 0, 0);
            z = __builtin_amdgcn_mfma_f32_16x16x32_bf16(kf1, qf[1], z, 0, 0, 0);
            s[nt] = z;
        }
        __builtin_amdgcn_s_setprio(0);

        // causal mask (diagonal tile only); values already in log2 domain
        if (kt == qt) {
#pragma unroll
            for (int nt = 0; nt < 4; ++nt)
#pragma unroll
                for (int r = 0; r < 4; ++r)
                    if ((nt * 16 + quad * 4 + r) > qin) s[nt][r] = -INFINITY;
        }

        // per-lane max (tree); cross-lane reduce only if the gate fires
        float a0 = fmaxf(fmaxf(s[0][0], s[0][1]), fmaxf(s[0][2], s[0][3]));
        float a1 = fmaxf(fmaxf(s[1][0], s[1][1]), fmaxf(s[1][2], s[1][3]));
        float a2 = fmaxf(fmaxf(s[2][0], s[2][1]), fmaxf(s[2][2], s[2][3]));
        float a3 = fmaxf(fmaxf(s[3][0], s[3][1]), fmaxf(s[3][2], s[3][3]));
        float lm = fmaxf(fmaxf(a0, a1), fmaxf(a2, a3));
        if (__any(lm > mrow + 8.f)) {
            float tm = fmaxf(lm, __shfl_xor(lm, 16, 64));
            tm = fmaxf(tm, __shfl_xor(tm, 32, 64));
            float mnew = fmaxf(mrow, tm);
            float alpha = __builtin_amdgcn_exp2f(mrow - mnew);
            mrow = mnew;
            lrow *= alpha;
#pragma unroll
            for (int nt = 0; nt < 4; ++nt)
#pragma unroll
                for (int r = 0; r < 4; ++r) O[nt][r] *= alpha;
        }
#pragma unroll
        for (int nt = 0; nt < 4; ++nt)
#pragma unroll
            for (int r = 0; r < 4; ++r)
                s[nt][r] = __builtin_amdgcn_exp2f(s[nt][r] - mrow);
        // per-lane partial sum only (cross-lane reduce deferred to epilogue)
        float r0s = (s[0][0] + s[0][1]) + (s[0][2] + s[0][3]);
        float r1s = (s[1][0] + s[1][1]) + (s[1][2] + s[1][3]);
        float r2s = (s[2][0] + s[2][1]) + (s[2][2] + s[2][3]);
        float r3s = (s[3][0] + s[3][1]) + (s[3][2] + s[3][3]);
        lrow += (r0s + r1s) + (r2s + r3s);

        // P -> per-wave LDS, k-consecutive, XOR-swizzled pad-free rows
#pragma unroll
        for (int nt = 0; nt < 4; ++nt) {
            uint2 u;
            u.x = pk2(s[nt][0], s[nt][1]);
            u.y = pk2(s[nt][2], s[nt][3]);
            *(uint2*)(Pb + ((nt * 32 + quad * 8) ^ hsw)) = u;
        }

        // P A/B-frags (same-wave LDS RAW, in-order per wave)
        short8 pf0 = *(const short8*)(Pb + ((quad * 16) ^ hsw));
        short8 pf1 = *(const short8*)(Pb + ((64 + quad * 16) ^ hsw));

        // O^T += V^T-frag x P-frag
        __builtin_amdgcn_s_setprio(1);
#pragma unroll
        for (int nt = 0; nt < 4; ++nt) {
            int r = nt * 16 + lx;
            short8 vf0 = *(const short8*)&Vs[r * 64 + ((quad ^ (r & 7)) << 3)];
            short8 vf1 = *(const short8*)&Vs[r * 64 + (((4 + quad) ^ (r & 7)) << 3)];
            O[nt] = __builtin_amdgcn_mfma_f32_16x16x32_bf16(vf0, pf0, O[nt], 0, 0, 0);
            O[nt] = __builtin_amdgcn_mfma_f32_16x16x32_bf16(vf1, pf1, O[nt], 0, 0, 0);
        }
        __builtin_amdgcn_s_setprio(0);
    }

    // epilogue: finish the deferred l-reduce, then write O rows
    {
        lrow += __shfl_xor(lrow, 16, 64);
        lrow += __shfl_xor(lrow, 32, 64);
        float invl = 1.f / lrow;
        size_t ro = qbase + (size_t)(qt * 64 + w * 16 + lx) * D_MODEL;
#pragma unroll
        for (int nt = 0; nt < 4; ++nt) {
            uint2 u;
            u.x = pk2(O[nt][0] * invl, O[nt][1] * invl);
            u.y = pk2(O[nt][2] * invl, O[nt][3] * invl);
            *(uint2*)&Hc[ro + nt * 16 + quad * 4] = u;
        }
    }
}

__global__ __launch_bounds__(256) void flash_mfma(
    const ushort_t* __restrict__ Qp, const ushort_t* __restrict__ Kp,
    const ushort_t* __restrict__ Vt, ushort_t* __restrict__ Hc)
{
    __shared__ ushort_t Ks0[64 * 64], Ks1[64 * 64];
    __shared__ ushort_t Vs0[64 * 64], Vs1[64 * 64];
    __shared__ __align__(16) ushort_t Ps[4][16 * 64];   // total LDS = 40960B

    // Block swizzle: flat%8 == bh%8 -> all 32 q-tiles of a head land on one
    // XCD; per-CU slot quartet gets qt = {u, 31-u, (u+8)&31, 31-((u+8)&31)}
    // -> 66 k-iters per CU, balanced.
    const int flat = blockIdx.x;          // 0..1023
    const int c  = flat & 7;              // XCD
    const int j  = flat >> 3;             // 0..127 within XCD
    const int cu = j & 31;                // CU slot heuristic
    const int m  = j >> 5;                // 0..3 co-residency slot
    const int bh = c + (m << 3);          // head group: 4 heads per XCD
    const int u  = (cu + ((m >> 1) << 3)) & 31;
    const int qt = (m & 1) ? (NQT - 1 - u) : u;
    const int b = bh >> 4, h = bh & 15;

    const size_t qbase = (size_t)(b * SEQ) * D_MODEL + h * DK;
    const size_t vbase = (size_t)bh * DK * SEQ;

    flash_tile(qt, qbase, vbase, Qp, Kp, Vt, Hc, Ks0, Ks1, Vs0, Vs1, Ps);
}

extern "C" void kernel_launch(void* const* d_in, const int* in_sizes, int n_in,
                              void* d_out, int out_size, void* d_ws, size_t ws_size,
                              hipStream_t stream) {
    const float* inQ = (const float*)d_in[0];
    const float* inK = (const float*)d_in[1];
    const float* inV = (const float*)d_in[2];
    const float* Wq  = (const float*)d_in[3];
    const float* bq  = (const float*)d_in[4];
    const float* Wk  = (const float*)d_in[5];
    const float* bk  = (const float*)d_in[6];
    const float* Wv  = (const float*)d_in[7];
    const float* bv  = (const float*)d_in[8];
    const float* Wo  = (const float*)d_in[9];
    const float* bo  = (const float*)d_in[10];
    float* out = (float*)d_out;

    const size_t NI = (size_t)MROWS * D_MODEL;      // 4M
    const size_t NW = (size_t)D_MODEL * D_MODEL;    // 1M
    ushort_t* ws  = (ushort_t*)d_ws;
    ushort_t* Wqb = ws;                // bf16 weights
    ushort_t* Wkb = Wqb + NW;
    ushort_t* Wvb = Wkb + NW;
    ushort_t* Wob = Wvb + NW;
    ushort_t* Qp  = Wob + NW;          // projections
    ushort_t* Kp  = Qp  + NI;
    ushort_t* Vtg = Kp  + NI;          // V^T [B*H][DK][SEQ]
    ushort_t* Hc  = Vtg + NI;

    // fp32 -> bf16, weights only (input cvt fused into gemm_mfma staging)
    cvt_bf16<<<dim3(NW / 1024, 4), 256, 0, stream>>>(
        Wq, Wk, Wv, Wo, Wqb, Wkb, Wvb, Wob);

    // fused QKV projection; Q pre-scaled by 1/sqrt(dk)*log2(e).
    // Inputs read as fp32 with in-kernel cvt; V^T via transposed gemm.
    const float qsc = 0.125f * 1.44269504088896340736f;
    GemmArgs aq{inQ, Wqb, bq, (void*)Qp, 0, qsc};
    GemmArgs ak{inK, Wkb, bk, (void*)Kp, 0, 1.0f};
    GemmArgs av{inV, Wvb, bv, (void*)Vtg, 1, 1.0f};
    gemm_mfma<<<dim3(MROWS / 128, D_MODEL / 128, 3), 256, 0, stream>>>(aq, ak, av);

    // attention (r13 structure: 1024 blocks, 4/CU, XCD-grouped)
    flash_mfma<<<dim3(NQT * BATCH * NHEADS), 256, 0, stream>>>(Qp, Kp, Vtg, Hc);

    // output projection (fp32 out), 64x128 single-buffer tiles, 512 blocks
    gemm_o<<<dim3(MROWS / 64, D_MODEL / 128), 256, 0, stream>>>(Hc, Wob, bo, out);
}